// Round 16
// baseline (208.435 us; speedup 1.0000x reference)
//
#include <hip/hip_runtime.h>
#include <hip/hip_bf16.h>

typedef unsigned short u16;
typedef short bf16x8 __attribute__((ext_vector_type(8)));
typedef float f32x4 __attribute__((ext_vector_type(4)));
typedef float f32x16 __attribute__((ext_vector_type(16)));
typedef unsigned short u16x4 __attribute__((ext_vector_type(4)));
typedef unsigned u32x4 __attribute__((ext_vector_type(4)));

// scores pre-scaled by log2(e)/8 (folded into Wq, bq) so softmax is pure exp2
#define SCALE_Q 0.18033688011112042f

__device__ __forceinline__ u16 f2b(float f) {
    __hip_bfloat16 h = __float2bfloat16(f);   // hw v_cvt (RNE) on gfx950
    return *reinterpret_cast<u16*>(&h);
}

__device__ __forceinline__ unsigned cvt_pk_bf16(float lo, float hi) {
    unsigned r;
    asm("v_cvt_pk_bf16_f32 %0, %1, %2" : "=v"(r) : "v"(lo), "v"(hi));
    return r;
}

// single-instruction exp2/rcp via BUILTINS (hazard-safe; R10's inline-asm
// version defeated TRANS wait-state insertion -> wrong values)
#define hw_exp2 __builtin_amdgcn_exp2f
#define hw_rcp  __builtin_amdgcn_rcpf

__device__ __forceinline__ void load_lds16(const void* g, void* l) {
    __builtin_amdgcn_global_load_lds(
        (const __attribute__((address_space(1))) void*)g,
        (__attribute__((address_space(3))) void*)l, 16, 0, 0);
}

// ---------------- prep: hidden * channel_importance -> bf16 ----------------
__global__ __launch_bounds__(256) void prep_hidden(
    const float* __restrict__ x, const float* __restrict__ ci, u16* __restrict__ hbuf) {
    size_t i = ((size_t)blockIdx.x * 256 + threadIdx.x) * 4;
    float4 v = *(const float4*)(x + i);
    int c = (int)(i % 768);
    u16x4 o;
    o.x = f2b(v.x * ci[c]);     o.y = f2b(v.y * ci[c + 1]);
    o.z = f2b(v.z * ci[c + 2]); o.w = f2b(v.w * ci[c + 3]);
    *(u16x4*)(hbuf + i) = o;
}

// ---------------- prep: transpose weights to [N][K] bf16 ----------------
__global__ __launch_bounds__(256) void transpose_w(
    const float* __restrict__ Wq, const float* __restrict__ Wk,
    const float* __restrict__ Wv, const float* __restrict__ Wo,
    const float* __restrict__ cc, u16* __restrict__ wqkvt, u16* __restrict__ wot) {
    __shared__ float tile[32][33];
    int z = blockIdx.z;
    const float* src = (z == 0) ? Wq : (z == 1) ? Wk : (z == 2) ? Wv : Wo;
    u16* dst = (z < 3) ? (wqkvt + (size_t)z * 768 * 768) : wot;
    int tx = threadIdx.x & 31, ty = threadIdx.x >> 5;
    int k0 = blockIdx.x * 32, n0 = blockIdx.y * 32;
    #pragma unroll
    for (int i = ty; i < 32; i += 8) {
        float v = src[(size_t)(k0 + i) * 768 + n0 + tx];
        if (z == 3) v *= cc[k0 + i];
        if (z == 0) v *= SCALE_Q;
        tile[i][tx] = v;
    }
    __syncthreads();
    #pragma unroll
    for (int i = ty; i < 32; i += 8)
        dst[(size_t)(n0 + i) * 768 + k0 + tx] = f2b(tile[tx][i]);
}

__global__ __launch_bounds__(256) void bias_cat(
    const float* __restrict__ bq, const float* __restrict__ bk,
    const float* __restrict__ bv, float* __restrict__ biasq) {
    int i = blockIdx.x * 256 + threadIdx.x;
    biasq[i] = (i < 768) ? bq[i] * SCALE_Q : (i < 1536) ? bk[i - 768] : bv[i - 1536];
}

// -------- GEMM: C = A @ Bt^T + bias (3-slot ring, FINE 2-phase interleave) --
// BM=256, BN=128, BK=64, 512 thr (8 waves 4Mx2N). 3 LDS slots (144 KB).
// Each K-tile = 2 phases (ks=0/1); each phase: issue 3 of kt+2's staging
// loads + 8 ds_read_b128 + 16 MFMA, ending lgkmcnt(0); s_barrier. vmcnt(6)
// once per K-tile AFTER kt+2 fully issued: in-order retirement => kt+1's 6
// landed while kt+2's 6 stay in flight -- never drains to 0 (m97's stall).
// R15 lesson: coarse stage-all/compute-all at 1 block/CU idles the CU at
// phase boundaries (m196); the per-phase interleave is the lever.
// Race audit: slot(kt+2)=slot(kt-1); its last reads drained by the explicit
// per-phase lgkmcnt(0) BEFORE the barrier preceding the staging issue (raw
// s_barrier does not drain DS; MFMAs may sink past asm but only use regs).
template <int F32OUT>
__global__ __launch_bounds__(512) void gemm_bt(
    const u16* __restrict__ A, const u16* __restrict__ Bt,
    const float* __restrict__ bias, void* __restrict__ Cout,
    int M, int N, int K, int NTN) {
    __shared__ u16 lds[3 * 24576];   // slot: A 256x64 (16384 u16) + B 128x64 (8192)
    int nwg = gridDim.x;
    int bid = blockIdx.x;
    int wg = ((nwg & 7) == 0) ? ((bid & 7) * (nwg >> 3) + (bid >> 3)) : bid;
    int mt = wg / NTN, nt = wg % NTN;
    int row0 = mt << 8, col0 = nt << 7;
    int tid = threadIdx.x;
    int lane = tid & 63, wv = tid >> 6;
    int wm = (wv >> 1) << 6;          // 0,64,128,192
    int wn = (wv & 1) << 6;           // 0,64
    int l15 = lane & 15, hi = lane >> 4;

    f32x4 acc[4][4] = {};

    // part 0: A chunks 0..1023 + B chunks 0..511; part 1: the rest (3 loads each)
    auto STAGE_PART = [&](int kt, int s, int part) {
        u16* sl = &lds[s * 24576];
        size_t kof = (size_t)kt << 6;
        int pa0 = part * 2;
        #pragma unroll
        for (int p = 0; p < 2; ++p) {
            int c = (pa0 + p) * 512 + tid;
            int rr = c >> 3, cc2 = (c & 7) ^ (rr & 7);
            load_lds16(A + (size_t)(row0 + rr) * K + kof + cc2 * 8,
                       &sl[((pa0 + p) * 512 + (wv << 6)) << 3]);
        }
        {
            int c = part * 512 + tid;
            int rr = c >> 3, cc2 = (c & 7) ^ (rr & 7);
            load_lds16(Bt + (size_t)(col0 + rr) * K + kof + cc2 * 8,
                       &sl[16384 + ((part * 512 + (wv << 6)) << 3)]);
        }
    };

    auto PHASE = [&](int s, int ks) {   // 8 ds_read_b128 + 16 MFMA
        u16* sA = &lds[s * 24576];
        u16* sB = sA + 16384;
        bf16x8 af[4], bf[4];
        #pragma unroll
        for (int i = 0; i < 4; ++i) {
            int ra = wm + i * 16 + l15;
            af[i] = *(const bf16x8*)&sA[ra * 64 + (((ks << 2) + hi) ^ (ra & 7)) * 8];
            int rb = wn + i * 16 + l15;
            bf[i] = *(const bf16x8*)&sB[rb * 64 + (((ks << 2) + hi) ^ (rb & 7)) * 8];
        }
        __builtin_amdgcn_s_setprio(1);
        #pragma unroll
        for (int mi = 0; mi < 4; ++mi)
            #pragma unroll
            for (int ni = 0; ni < 4; ++ni)
                acc[mi][ni] = __builtin_amdgcn_mfma_f32_16x16x32_bf16(
                    af[mi], bf[ni], acc[mi][ni], 0, 0, 0);
        __builtin_amdgcn_s_setprio(0);
    };

    int nkt = K >> 6;                 // 12 for K=768
    // prologue: stage K-tiles 0,1 into slots 0,1 (12 loads/thread)
    STAGE_PART(0, 0, 0); STAGE_PART(0, 0, 1);
    STAGE_PART(1, 1, 0); STAGE_PART(1, 1, 1);
    asm volatile("s_waitcnt vmcnt(6)" ::: "memory");   // tile0's 6 landed
    asm volatile("s_barrier" ::: "memory");

    int s = 0;
    for (int kt = 0; kt < nkt; ++kt) {
        int s2 = s + 2; if (s2 >= 3) s2 -= 3;
        bool st = kt + 2 < nkt;
        // ---- phase A (ks=0) ----
        if (st) STAGE_PART(kt + 2, s2, 0);
        PHASE(s, 0);
        asm volatile("s_waitcnt lgkmcnt(0)" ::: "memory");
        asm volatile("s_barrier" ::: "memory");
        // ---- phase B (ks=1) ----
        if (st) STAGE_PART(kt + 2, s2, 1);
        PHASE(s, 1);
        if (st)                  asm volatile("s_waitcnt vmcnt(6)" ::: "memory");
        else if (kt + 2 == nkt)  asm volatile("s_waitcnt vmcnt(0)" ::: "memory");
        asm volatile("s_waitcnt lgkmcnt(0)" ::: "memory");
        asm volatile("s_barrier" ::: "memory");
        if (++s == 3) s = 0;
    }

    #pragma unroll
    for (int mi = 0; mi < 4; ++mi) {
        int rbase = row0 + wm + mi * 16 + hi * 4;
        #pragma unroll
        for (int ni = 0; ni < 4; ++ni) {
            int c = col0 + wn + ni * 16 + l15;
            float bv = bias[c];
            #pragma unroll
            for (int j = 0; j < 4; ++j) {
                float o = acc[mi][ni][j] + bv;
                if (F32OUT) ((float*)Cout)[(size_t)(rbase + j) * N + c] = o;
                else        ((u16*)Cout)[(size_t)(rbase + j) * N + c] = f2b(o);
            }
        }
    }
}

// ---------------- flash attention (QBLK=256: 8 waves, KVBLK=64) ------------
// (unchanged from R14: 512 thr, launch_bounds(512,4), kvb-seq, zero-shuffle
// PV via b2<->b3 V columns, lane-local VALU-L, builtin exp2/rcp.)
__global__ __launch_bounds__(512, 4) void attn_kernel(
    const u16* __restrict__ QKV, u16* __restrict__ ctx) {
    __shared__ u16 lK[2][64 * 64];    // K-tile [kv][d], XOR-swizzled 16B chunks
    __shared__ u16 lV[2][64 * 68];    // V^T tile [d][kv'], kv' = b2<->b3 swap, +4 pad

    int bid = blockIdx.x;
    int wg = (bid & 7) * 96 + (bid >> 3);   // XCD swizzle, nwg=768
    int bh = wg >> 2, qt = wg & 3;
    int b = bh / 12, h = bh % 12;
    int tid = threadIdx.x;
    int lane = tid & 63, wv = tid >> 6;     // wv 0..7
    int l31 = lane & 31;
    int hb = lane >> 5;

    const u16* Qb = QKV + (size_t)b * 1024 * 2304 + h * 64;
    const u16* Kb = Qb + 768;
    const u16* Vb = Qb + 1536;

    int qrow0 = qt * 256 + wv * 32;

    bf16x8 qf[4];
    #pragma unroll
    for (int ks = 0; ks < 4; ++ks)
        qf[ks] = *(const bf16x8*)(Qb + (size_t)(qrow0 + l31) * 2304 + ks * 16 + hb * 8);

    f32x16 accO0 = {}, accO1 = {};
    float lacc = 0.f;

    int krr = tid >> 3;
    int kcc = (tid & 7) ^ (krr & 7);
    bool vstage = tid < 256;
    int jj0 = (tid & 31) * 2;
    int jjs = (jj0 & ~12) | ((jj0 & 4) << 1) | ((jj0 & 8) >> 1);  // b2<->b3 swap
    int d0v = ((tid >> 5) & 7) << 3;

    load_lds16(Kb + (size_t)krr * 2304 + kcc * 8, &lK[0][(wv << 6) << 3]);
    if (vstage) {
        bf16x8 g0 = *(const bf16x8*)(Vb + (size_t)jj0 * 2304 + d0v);
        bf16x8 g1 = *(const bf16x8*)(Vb + (size_t)(jj0 + 1) * 2304 + d0v);
        const unsigned* a0 = (const unsigned*)&g0;
        const unsigned* a1 = (const unsigned*)&g1;
        #pragma unroll
        for (int w = 0; w < 4; ++w) {
            *(unsigned*)&lV[0][(d0v + 2 * w) * 68 + jjs] =
                __builtin_amdgcn_perm(a1[w], a0[w], 0x05040100);
            *(unsigned*)&lV[0][(d0v + 2 * w + 1) * 68 + jjs] =
                __builtin_amdgcn_perm(a1[w], a0[w], 0x07060302);
        }
    }
    __syncthreads();

    int cur = 0;
    for (int t = 0; t < 16; ++t) {
        bf16x8 nv0, nv1;
        if (t < 15) {
            size_t kt1 = (size_t)(t + 1) * 64;
            load_lds16(Kb + (kt1 + krr) * 2304 + kcc * 8, &lK[cur ^ 1][(wv << 6) << 3]);
            if (vstage) {
                nv0 = *(const bf16x8*)(Vb + (kt1 + jj0) * 2304 + d0v);
                nv1 = *(const bf16x8*)(Vb + (kt1 + jj0 + 1) * 2304 + d0v);
            }
        }

        #pragma unroll
        for (int kvb = 0; kvb < 2; ++kvb) {
            f32x16 accs = {};
            __builtin_amdgcn_s_setprio(1);
            #pragma unroll
            for (int ks = 0; ks < 4; ++ks) {
                bf16x8 kf = *(const bf16x8*)&lK[cur][
                    (kvb * 32 + l31) * 64 + (((ks << 1) + hb) ^ (l31 & 7)) * 8];
                accs = __builtin_amdgcn_mfma_f32_32x32x16_bf16(kf, qf[ks], accs, 0, 0, 0);
            }
            __builtin_amdgcn_s_setprio(0);

            unsigned W[8];
            float ls = 0.f;
            #pragma unroll
            for (int w = 0; w < 8; ++w) {
                float e0 = hw_exp2(accs[2 * w]);
                float e1 = hw_exp2(accs[2 * w + 1]);
                ls += e0 + e1;
                W[w] = cvt_pk_bf16(e0, e1);
            }
            lacc += ls;

            __builtin_amdgcn_s_setprio(1);
            #pragma unroll
            for (int mm = 0; mm < 2; ++mm) {
                int m = kvb * 2 + mm;
                u32x4 pw;
                pw.x = W[4 * mm];     pw.y = W[4 * mm + 1];
                pw.z = W[4 * mm + 2]; pw.w = W[4 * mm + 3];
                bf16x8 pa = *(bf16x8*)&pw;
                bf16x8 vf0 = *(const bf16x8*)&lV[cur][l31 * 68 + m * 16 + hb * 8];
                bf16x8 vf1 = *(const bf16x8*)&lV[cur][(32 + l31) * 68 + m * 16 + hb * 8];
                accO0 = __builtin_amdgcn_mfma_f32_32x32x16_bf16(pa, vf0, accO0, 0, 0, 0);
                accO1 = __builtin_amdgcn_mfma_f32_32x32x16_bf16(pa, vf1, accO1, 0, 0, 0);
            }
            __builtin_amdgcn_s_setprio(0);
        }

        if (t < 15 && vstage) {
            const unsigned* a0 = (const unsigned*)&nv0;
            const unsigned* a1 = (const unsigned*)&nv1;
            #pragma unroll
            for (int w = 0; w < 4; ++w) {
                *(unsigned*)&lV[cur ^ 1][(d0v + 2 * w) * 68 + jjs] =
                    __builtin_amdgcn_perm(a1[w], a0[w], 0x05040100);
                *(unsigned*)&lV[cur ^ 1][(d0v + 2 * w + 1) * 68 + jjs] =
                    __builtin_amdgcn_perm(a1[w], a0[w], 0x07060302);
            }
        }

        __syncthreads();
        cur ^= 1;
    }

    float lsum = lacc + __shfl_xor(lacc, 32);
    #pragma unroll
    for (int r = 0; r < 16; ++r) {
        int q = (r & 3) + 8 * (r >> 2) + hb * 4;
        float Lr = __shfl(lsum, q);
        float inv = hw_rcp(Lr);
        size_t row = (size_t)(b * 1024 + qrow0 + q);
        ctx[row * 768 + h * 64 + l31]      = f2b(accO0[r] * inv);
        ctx[row * 768 + h * 64 + 32 + l31] = f2b(accO1[r] * inv);
    }
}

// ---------------- launcher ----------------
extern "C" void kernel_launch(void* const* d_in, const int* in_sizes, int n_in,
                              void* d_out, int out_size, void* d_ws, size_t ws_size,
                              hipStream_t stream) {
    const float* x  = (const float*)d_in[0];
    const float* ci = (const float*)d_in[1];
    const float* cc = (const float*)d_in[2];
    const float* Wq = (const float*)d_in[3];
    const float* bq = (const float*)d_in[4];
    const float* Wk = (const float*)d_in[5];
    const float* bk = (const float*)d_in[6];
    const float* Wv = (const float*)d_in[7];
    const float* bv = (const float*)d_in[8];
    const float* Wo = (const float*)d_in[9];
    const float* bo = (const float*)d_in[10];
    float* out = (float*)d_out;

    unsigned char* ws = (unsigned char*)d_ws;
    size_t off = 0;
    auto alloc = [&](size_t bytes) {
        void* p = ws + off;
        off += (bytes + 255) & ~(size_t)255;
        return p;
    };
    u16*   hbuf  = (u16*)  alloc((size_t)16384 * 768 * 2);
    u16*   wqkvt = (u16*)  alloc((size_t)2304 * 768 * 2);
    u16*   wot   = (u16*)  alloc((size_t)768 * 768 * 2);
    float* biasq = (float*)alloc(2304 * 4);
    u16*   qkv   = (u16*)  alloc((size_t)16384 * 2304 * 2);
    u16*   ctx   = (u16*)  alloc((size_t)16384 * 768 * 2);

    prep_hidden<<<12288, 256, 0, stream>>>(x, ci, hbuf);
    transpose_w<<<dim3(24, 24, 4), 256, 0, stream>>>(Wq, Wk, Wv, Wo, cc, wqkvt, wot);
    bias_cat<<<9, 256, 0, stream>>>(bq, bk, bv, biasq);
    gemm_bt<0><<<1152, 512, 0, stream>>>(hbuf, wqkvt, biasq, qkv, 16384, 2304, 768, 18);
    attn_kernel<<<768, 512, 0, stream>>>(qkv, ctx);
    gemm_bt<1><<<384, 512, 0, stream>>>(ctx, wot, bo, out, 16384, 768, 768, 6);
}

// Round 17
// 189.134 us; speedup vs baseline: 1.1020x; 1.1020x over previous
//
#include <hip/hip_runtime.h>
#include <hip/hip_bf16.h>

typedef unsigned short u16;
typedef short bf16x8 __attribute__((ext_vector_type(8)));
typedef float f32x4 __attribute__((ext_vector_type(4)));
typedef float f32x16 __attribute__((ext_vector_type(16)));
typedef unsigned short u16x4 __attribute__((ext_vector_type(4)));
typedef unsigned u32x4 __attribute__((ext_vector_type(4)));

// scores pre-scaled by log2(e)/8 (folded into Wq, bq) so softmax is pure exp2
#define SCALE_Q 0.18033688011112042f

__device__ __forceinline__ u16 f2b(float f) {
    __hip_bfloat16 h = __float2bfloat16(f);   // hw v_cvt (RNE) on gfx950
    return *reinterpret_cast<u16*>(&h);
}

__device__ __forceinline__ unsigned cvt_pk_bf16(float lo, float hi) {
    unsigned r;
    asm("v_cvt_pk_bf16_f32 %0, %1, %2" : "=v"(r) : "v"(lo), "v"(hi));
    return r;
}

// single-instruction exp2/rcp via BUILTINS (hazard-safe; R10's inline-asm
// version defeated TRANS wait-state insertion -> wrong values)
#define hw_exp2 __builtin_amdgcn_exp2f
#define hw_rcp  __builtin_amdgcn_rcpf

__device__ __forceinline__ void load_lds16(const void* g, void* l) {
    __builtin_amdgcn_global_load_lds(
        (const __attribute__((address_space(1))) void*)g,
        (__attribute__((address_space(3))) void*)l, 16, 0, 0);
}

// ---------------- prep: hidden * channel_importance -> bf16 ----------------
__global__ __launch_bounds__(256) void prep_hidden(
    const float* __restrict__ x, const float* __restrict__ ci, u16* __restrict__ hbuf) {
    size_t i = ((size_t)blockIdx.x * 256 + threadIdx.x) * 4;
    float4 v = *(const float4*)(x + i);
    int c = (int)(i % 768);
    u16x4 o;
    o.x = f2b(v.x * ci[c]);     o.y = f2b(v.y * ci[c + 1]);
    o.z = f2b(v.z * ci[c + 2]); o.w = f2b(v.w * ci[c + 3]);
    *(u16x4*)(hbuf + i) = o;
}

// ---------------- prep: transpose weights to [N][K] bf16 ----------------
__global__ __launch_bounds__(256) void transpose_w(
    const float* __restrict__ Wq, const float* __restrict__ Wk,
    const float* __restrict__ Wv, const float* __restrict__ Wo,
    const float* __restrict__ cc, u16* __restrict__ wqkvt, u16* __restrict__ wot) {
    __shared__ float tile[32][33];
    int z = blockIdx.z;
    const float* src = (z == 0) ? Wq : (z == 1) ? Wk : (z == 2) ? Wv : Wo;
    u16* dst = (z < 3) ? (wqkvt + (size_t)z * 768 * 768) : wot;
    int tx = threadIdx.x & 31, ty = threadIdx.x >> 5;
    int k0 = blockIdx.x * 32, n0 = blockIdx.y * 32;
    #pragma unroll
    for (int i = ty; i < 32; i += 8) {
        float v = src[(size_t)(k0 + i) * 768 + n0 + tx];
        if (z == 3) v *= cc[k0 + i];
        if (z == 0) v *= SCALE_Q;
        tile[i][tx] = v;
    }
    __syncthreads();
    #pragma unroll
    for (int i = ty; i < 32; i += 8)
        dst[(size_t)(n0 + i) * 768 + k0 + tx] = f2b(tile[tx][i]);
}

__global__ __launch_bounds__(256) void bias_cat(
    const float* __restrict__ bq, const float* __restrict__ bk,
    const float* __restrict__ bv, float* __restrict__ biasq) {
    int i = blockIdx.x * 256 + threadIdx.x;
    biasq[i] = (i < 768) ? bq[i] * SCALE_Q : (i < 1536) ? bk[i - 768] : bv[i - 1536];
}

// ---------------- GEMM: C[M][N] = A[M][K] @ Bt[N][K]^T + bias ----------------
// R14's proven 2-barrier 128x128 structure (2 blocks/CU implicit overlap --
// R15/R16 pipeline ports both regressed), with the compute core switched to
// 32x32x16 MFMAs: 16 instr/K-tile/wave instead of 32, ~17% less matrix-pipe
// time (m119: 8.07 cyc/32k FLOP vs 4.85/16k). Operand/C layouts identical to
// the attn kernel's session-verified mappings.
template <int F32OUT>
__global__ __launch_bounds__(256) void gemm_bt(
    const u16* __restrict__ A, const u16* __restrict__ Bt,
    const float* __restrict__ bias, void* __restrict__ Cout,
    int M, int N, int K, int NTN) {
    __shared__ u16 lA[128 * 64];
    __shared__ u16 lB[128 * 64];
    int nwg = gridDim.x;
    int bid = blockIdx.x;
    int wg = ((nwg & 7) == 0) ? ((bid & 7) * (nwg >> 3) + (bid >> 3)) : bid;
    int mt = wg / NTN, nt = wg % NTN;
    int row0 = mt << 7, col0 = nt << 7;
    int tid = threadIdx.x;
    int lane = tid & 63, wv = tid >> 6;
    int wm = (wv >> 1) * 64, wn = (wv & 1) * 64;
    int l31 = lane & 31, hb = lane >> 5;

    f32x16 acc[2][2] = {};   // 2x2 frags of 32x32 = 64x64 per wave

    for (int kt = 0; kt < K; kt += 64) {
        __syncthreads();
        #pragma unroll
        for (int p = 0; p < 4; ++p) {
            int cl = p * 256 + tid;
            int rr = cl >> 3;
            int cc = (cl & 7) ^ (rr & 7);
            int lo = (p * 256 + (wv << 6)) << 3;
            load_lds16(A + (size_t)(row0 + rr) * K + kt + cc * 8, &lA[lo]);
            load_lds16(Bt + (size_t)(col0 + rr) * K + kt + cc * 8, &lB[lo]);
        }
        __syncthreads();
        __builtin_amdgcn_s_setprio(1);
        #pragma unroll
        for (int ks = 0; ks < 4; ++ks) {       // 4 slices of 16 k
            bf16x8 af[2], bf[2];
            #pragma unroll
            for (int i = 0; i < 2; ++i) {
                int ra = wm + i * 32 + l31;
                af[i] = *(const bf16x8*)&lA[ra * 64 + (((ks << 1) + hb) ^ (ra & 7)) * 8];
                int rb = wn + i * 32 + l31;
                bf[i] = *(const bf16x8*)&lB[rb * 64 + (((ks << 1) + hb) ^ (rb & 7)) * 8];
            }
            #pragma unroll
            for (int mi = 0; mi < 2; ++mi)
                #pragma unroll
                for (int ni = 0; ni < 2; ++ni)
                    acc[mi][ni] = __builtin_amdgcn_mfma_f32_32x32x16_bf16(
                        af[mi], bf[ni], acc[mi][ni], 0, 0, 0);
        }
        __builtin_amdgcn_s_setprio(0);
    }

    // C layout (verified m74/m101 + this session's attn epilogue):
    // col = l31 (B-operand lane), row = (r&3) + 8*(r>>2) + 4*hb
    #pragma unroll
    for (int mi = 0; mi < 2; ++mi) {
        #pragma unroll
        for (int ni = 0; ni < 2; ++ni) {
            int c = col0 + wn + ni * 32 + l31;
            float bv = bias[c];
            #pragma unroll
            for (int r = 0; r < 16; ++r) {
                int row = row0 + wm + mi * 32 + (r & 3) + 8 * (r >> 2) + 4 * hb;
                float o = acc[mi][ni][r] + bv;
                if (F32OUT) ((float*)Cout)[(size_t)row * N + c] = o;
                else        ((u16*)Cout)[(size_t)row * N + c] = f2b(o);
            }
        }
    }
}

// ---------------- flash attention (QBLK=256: 8 waves, KVBLK=64) ------------
// (unchanged from R14: 512 thr, launch_bounds(512,4) -- no spills, 2 blocks/CU,
// kvb-seq, zero-shuffle PV via b2<->b3 V columns, lane-local VALU-L,
// builtin exp2/rcp.)
__global__ __launch_bounds__(512, 4) void attn_kernel(
    const u16* __restrict__ QKV, u16* __restrict__ ctx) {
    __shared__ u16 lK[2][64 * 64];    // K-tile [kv][d], XOR-swizzled 16B chunks
    __shared__ u16 lV[2][64 * 68];    // V^T tile [d][kv'], kv' = b2<->b3 swap, +4 pad

    int bid = blockIdx.x;
    int wg = (bid & 7) * 96 + (bid >> 3);   // XCD swizzle, nwg=768
    int bh = wg >> 2, qt = wg & 3;
    int b = bh / 12, h = bh % 12;
    int tid = threadIdx.x;
    int lane = tid & 63, wv = tid >> 6;     // wv 0..7
    int l31 = lane & 31;
    int hb = lane >> 5;

    const u16* Qb = QKV + (size_t)b * 1024 * 2304 + h * 64;
    const u16* Kb = Qb + 768;
    const u16* Vb = Qb + 1536;

    int qrow0 = qt * 256 + wv * 32;

    bf16x8 qf[4];
    #pragma unroll
    for (int ks = 0; ks < 4; ++ks)
        qf[ks] = *(const bf16x8*)(Qb + (size_t)(qrow0 + l31) * 2304 + ks * 16 + hb * 8);

    f32x16 accO0 = {}, accO1 = {};
    float lacc = 0.f;

    int krr = tid >> 3;
    int kcc = (tid & 7) ^ (krr & 7);
    bool vstage = tid < 256;
    int jj0 = (tid & 31) * 2;
    int jjs = (jj0 & ~12) | ((jj0 & 4) << 1) | ((jj0 & 8) >> 1);  // b2<->b3 swap
    int d0v = ((tid >> 5) & 7) << 3;

    load_lds16(Kb + (size_t)krr * 2304 + kcc * 8, &lK[0][(wv << 6) << 3]);
    if (vstage) {
        bf16x8 g0 = *(const bf16x8*)(Vb + (size_t)jj0 * 2304 + d0v);
        bf16x8 g1 = *(const bf16x8*)(Vb + (size_t)(jj0 + 1) * 2304 + d0v);
        const unsigned* a0 = (const unsigned*)&g0;
        const unsigned* a1 = (const unsigned*)&g1;
        #pragma unroll
        for (int w = 0; w < 4; ++w) {
            *(unsigned*)&lV[0][(d0v + 2 * w) * 68 + jjs] =
                __builtin_amdgcn_perm(a1[w], a0[w], 0x05040100);
            *(unsigned*)&lV[0][(d0v + 2 * w + 1) * 68 + jjs] =
                __builtin_amdgcn_perm(a1[w], a0[w], 0x07060302);
        }
    }
    __syncthreads();

    int cur = 0;
    for (int t = 0; t < 16; ++t) {
        bf16x8 nv0, nv1;
        if (t < 15) {
            size_t kt1 = (size_t)(t + 1) * 64;
            load_lds16(Kb + (kt1 + krr) * 2304 + kcc * 8, &lK[cur ^ 1][(wv << 6) << 3]);
            if (vstage) {
                nv0 = *(const bf16x8*)(Vb + (kt1 + jj0) * 2304 + d0v);
                nv1 = *(const bf16x8*)(Vb + (kt1 + jj0 + 1) * 2304 + d0v);
            }
        }

        #pragma unroll
        for (int kvb = 0; kvb < 2; ++kvb) {
            f32x16 accs = {};
            __builtin_amdgcn_s_setprio(1);
            #pragma unroll
            for (int ks = 0; ks < 4; ++ks) {
                bf16x8 kf = *(const bf16x8*)&lK[cur][
                    (kvb * 32 + l31) * 64 + (((ks << 1) + hb) ^ (l31 & 7)) * 8];
                accs = __builtin_amdgcn_mfma_f32_32x32x16_bf16(kf, qf[ks], accs, 0, 0, 0);
            }
            __builtin_amdgcn_s_setprio(0);

            unsigned W[8];
            float ls = 0.f;
            #pragma unroll
            for (int w = 0; w < 8; ++w) {
                float e0 = hw_exp2(accs[2 * w]);
                float e1 = hw_exp2(accs[2 * w + 1]);
                ls += e0 + e1;
                W[w] = cvt_pk_bf16(e0, e1);
            }
            lacc += ls;

            __builtin_amdgcn_s_setprio(1);
            #pragma unroll
            for (int mm = 0; mm < 2; ++mm) {
                int m = kvb * 2 + mm;
                u32x4 pw;
                pw.x = W[4 * mm];     pw.y = W[4 * mm + 1];
                pw.z = W[4 * mm + 2]; pw.w = W[4 * mm + 3];
                bf16x8 pa = *(bf16x8*)&pw;
                bf16x8 vf0 = *(const bf16x8*)&lV[cur][l31 * 68 + m * 16 + hb * 8];
                bf16x8 vf1 = *(const bf16x8*)&lV[cur][(32 + l31) * 68 + m * 16 + hb * 8];
                accO0 = __builtin_amdgcn_mfma_f32_32x32x16_bf16(pa, vf0, accO0, 0, 0, 0);
                accO1 = __builtin_amdgcn_mfma_f32_32x32x16_bf16(pa, vf1, accO1, 0, 0, 0);
            }
            __builtin_amdgcn_s_setprio(0);
        }

        if (t < 15 && vstage) {
            const unsigned* a0 = (const unsigned*)&nv0;
            const unsigned* a1 = (const unsigned*)&nv1;
            #pragma unroll
            for (int w = 0; w < 4; ++w) {
                *(unsigned*)&lV[cur ^ 1][(d0v + 2 * w) * 68 + jjs] =
                    __builtin_amdgcn_perm(a1[w], a0[w], 0x05040100);
                *(unsigned*)&lV[cur ^ 1][(d0v + 2 * w + 1) * 68 + jjs] =
                    __builtin_amdgcn_perm(a1[w], a0[w], 0x07060302);
            }
        }

        __syncthreads();
        cur ^= 1;
    }

    float lsum = lacc + __shfl_xor(lacc, 32);
    #pragma unroll
    for (int r = 0; r < 16; ++r) {
        int q = (r & 3) + 8 * (r >> 2) + hb * 4;
        float Lr = __shfl(lsum, q);
        float inv = hw_rcp(Lr);
        size_t row = (size_t)(b * 1024 + qrow0 + q);
        ctx[row * 768 + h * 64 + l31]      = f2b(accO0[r] * inv);
        ctx[row * 768 + h * 64 + 32 + l31] = f2b(accO1[r] * inv);
    }
}

// ---------------- launcher ----------------
extern "C" void kernel_launch(void* const* d_in, const int* in_sizes, int n_in,
                              void* d_out, int out_size, void* d_ws, size_t ws_size,
                              hipStream_t stream) {
    const float* x  = (const float*)d_in[0];
    const float* ci = (const float*)d_in[1];
    const float* cc = (const float*)d_in[2];
    const float* Wq = (const float*)d_in[3];
    const float* bq = (const float*)d_in[4];
    const float* Wk = (const float*)d_in[5];
    const float* bk = (const float*)d_in[6];
    const float* Wv = (const float*)d_in[7];
    const float* bv = (const float*)d_in[8];
    const float* Wo = (const float*)d_in[9];
    const float* bo = (const float*)d_in[10];
    float* out = (float*)d_out;

    unsigned char* ws = (unsigned char*)d_ws;
    size_t off = 0;
    auto alloc = [&](size_t bytes) {
        void* p = ws + off;
        off += (bytes + 255) & ~(size_t)255;
        return p;
    };
    u16*   hbuf  = (u16*)  alloc((size_t)16384 * 768 * 2);
    u16*   wqkvt = (u16*)  alloc((size_t)2304 * 768 * 2);
    u16*   wot   = (u16*)  alloc((size_t)768 * 768 * 2);
    float* biasq = (float*)alloc(2304 * 4);
    u16*   qkv   = (u16*)  alloc((size_t)16384 * 2304 * 2);
    u16*   ctx   = (u16*)  alloc((size_t)16384 * 768 * 2);

    prep_hidden<<<12288, 256, 0, stream>>>(x, ci, hbuf);
    transpose_w<<<dim3(24, 24, 4), 256, 0, stream>>>(Wq, Wk, Wv, Wo, cc, wqkvt, wot);
    bias_cat<<<9, 256, 0, stream>>>(bq, bk, bv, biasq);
    gemm_bt<0><<<2304, 256, 0, stream>>>(hbuf, wqkvt, biasq, qkv, 16384, 2304, 768, 18);
    attn_kernel<<<768, 512, 0, stream>>>(qkv, ctx);
    gemm_bt<1><<<768, 256, 0, stream>>>(ctx, wot, bo, out, 16384, 768, 768, 6);
}

// Round 18
// 182.123 us; speedup vs baseline: 1.1445x; 1.0385x over previous
//
#include <hip/hip_runtime.h>
#include <hip/hip_bf16.h>

typedef unsigned short u16;
typedef short bf16x8 __attribute__((ext_vector_type(8)));
typedef float f32x4 __attribute__((ext_vector_type(4)));
typedef float f32x16 __attribute__((ext_vector_type(16)));
typedef unsigned short u16x4 __attribute__((ext_vector_type(4)));
typedef unsigned u32x4 __attribute__((ext_vector_type(4)));

// scores pre-scaled by log2(e)/8 (folded into Wq, bq) so softmax is pure exp2
#define SCALE_Q 0.18033688011112042f

__device__ __forceinline__ u16 f2b(float f) {
    __hip_bfloat16 h = __float2bfloat16(f);   // hw v_cvt (RNE) on gfx950
    return *reinterpret_cast<u16*>(&h);
}

__device__ __forceinline__ unsigned cvt_pk_bf16(float lo, float hi) {
    unsigned r;
    asm("v_cvt_pk_bf16_f32 %0, %1, %2" : "=v"(r) : "v"(lo), "v"(hi));
    return r;
}

// single-instruction exp2/rcp via BUILTINS (hazard-safe; R10's inline-asm
// version defeated TRANS wait-state insertion -> wrong values)
#define hw_exp2 __builtin_amdgcn_exp2f
#define hw_rcp  __builtin_amdgcn_rcpf

__device__ __forceinline__ void load_lds16(const void* g, void* l) {
    __builtin_amdgcn_global_load_lds(
        (const __attribute__((address_space(1))) void*)g,
        (__attribute__((address_space(3))) void*)l, 16, 0, 0);
}

// ---------------- prep: hidden -> bf16 (ci folded into W rows) -------------
__global__ __launch_bounds__(256) void prep_hidden(
    const float* __restrict__ x, u16* __restrict__ hbuf) {
    size_t i = ((size_t)blockIdx.x * 256 + threadIdx.x) * 4;
    float4 v = *(const float4*)(x + i);
    u16x4 o;
    o.x = f2b(v.x); o.y = f2b(v.y); o.z = f2b(v.z); o.w = f2b(v.w);
    *(u16x4*)(hbuf + i) = o;
}

// ---------------- prep: transpose weights to [N][K] bf16 ----------------
// z=0..2: Wq/Wk/Wv rows scaled by channel_importance (exact: (x*ci)@W =
// x@(diag(ci)W)); z=0 also by SCALE_Q; z=3: Wo rows scaled by context_importance.
__global__ __launch_bounds__(256) void transpose_w(
    const float* __restrict__ Wq, const float* __restrict__ Wk,
    const float* __restrict__ Wv, const float* __restrict__ Wo,
    const float* __restrict__ ci, const float* __restrict__ cc,
    u16* __restrict__ wqkvt, u16* __restrict__ wot) {
    __shared__ float tile[32][33];
    int z = blockIdx.z;
    const float* src = (z == 0) ? Wq : (z == 1) ? Wk : (z == 2) ? Wv : Wo;
    u16* dst = (z < 3) ? (wqkvt + (size_t)z * 768 * 768) : wot;
    int tx = threadIdx.x & 31, ty = threadIdx.x >> 5;
    int k0 = blockIdx.x * 32, n0 = blockIdx.y * 32;
    #pragma unroll
    for (int i = ty; i < 32; i += 8) {
        float v = src[(size_t)(k0 + i) * 768 + n0 + tx];
        if (z < 3)  v *= ci[k0 + i];
        else        v *= cc[k0 + i];
        if (z == 0) v *= SCALE_Q;
        tile[i][tx] = v;
    }
    __syncthreads();
    #pragma unroll
    for (int i = ty; i < 32; i += 8)
        dst[(size_t)(n0 + i) * 768 + k0 + tx] = f2b(tile[tx][i]);
}

__global__ __launch_bounds__(256) void bias_cat(
    const float* __restrict__ bq, const float* __restrict__ bk,
    const float* __restrict__ bv, float* __restrict__ biasq) {
    int i = blockIdx.x * 256 + threadIdx.x;
    biasq[i] = (i < 768) ? bq[i] * SCALE_Q : (i < 1536) ? bk[i - 768] : bv[i - 1536];
}

// ---------------- GEMM: C[M][N] = A[M][K] @ Bt[N][K]^T + bias ----------------
// R14's proven structure exactly: 128x128 tile, BK=64, 4 waves (2x2),
// 16x16x32 MFMA (the 16-row fragment pattern measures ZERO bank conflicts;
// R17's 32x32 port hit the stride-128B 4-way trap, 7M conflicts, -6%).
// 2 blocks/CU implicit wave overlap beats all tried pipeline ports
// (R15 coarse ring -20%, R16 fine 2-phase -22%).
template <int F32OUT>
__global__ __launch_bounds__(256) void gemm_bt(
    const u16* __restrict__ A, const u16* __restrict__ Bt,
    const float* __restrict__ bias, void* __restrict__ Cout,
    int M, int N, int K, int NTN) {
    __shared__ u16 lA[128 * 64];
    __shared__ u16 lB[128 * 64];
    int nwg = gridDim.x;
    int bid = blockIdx.x;
    int wg = ((nwg & 7) == 0) ? ((bid & 7) * (nwg >> 3) + (bid >> 3)) : bid;
    int mt = wg / NTN, nt = wg % NTN;
    int row0 = mt << 7, col0 = nt << 7;
    int tid = threadIdx.x;
    int lane = tid & 63, wv = tid >> 6;
    int wm = (wv >> 1) * 64, wn = (wv & 1) * 64;
    int l15 = lane & 15, hi = lane >> 4;

    f32x4 acc[4][4] = {};

    for (int kt = 0; kt < K; kt += 64) {
        __syncthreads();
        #pragma unroll
        for (int p = 0; p < 4; ++p) {
            int cl = p * 256 + tid;
            int rr = cl >> 3;
            int cc = (cl & 7) ^ (rr & 7);
            int lo = (p * 256 + (wv << 6)) << 3;
            load_lds16(A + (size_t)(row0 + rr) * K + kt + cc * 8, &lA[lo]);
            load_lds16(Bt + (size_t)(col0 + rr) * K + kt + cc * 8, &lB[lo]);
        }
        __syncthreads();
        __builtin_amdgcn_s_setprio(1);
        #pragma unroll
        for (int ks = 0; ks < 2; ++ks) {
            bf16x8 af[4], bf[4];
            #pragma unroll
            for (int i = 0; i < 4; ++i) {
                int ra = wm + i * 16 + l15;
                af[i] = *(const bf16x8*)&lA[ra * 64 + (((ks << 2) + hi) ^ (ra & 7)) * 8];
                int rb = wn + i * 16 + l15;
                bf[i] = *(const bf16x8*)&lB[rb * 64 + (((ks << 2) + hi) ^ (rb & 7)) * 8];
            }
            #pragma unroll
            for (int mi = 0; mi < 4; ++mi)
                #pragma unroll
                for (int ni = 0; ni < 4; ++ni)
                    acc[mi][ni] = __builtin_amdgcn_mfma_f32_16x16x32_bf16(
                        af[mi], bf[ni], acc[mi][ni], 0, 0, 0);
        }
        __builtin_amdgcn_s_setprio(0);
    }

    #pragma unroll
    for (int mi = 0; mi < 4; ++mi) {
        int rbase = row0 + wm + mi * 16 + hi * 4;
        #pragma unroll
        for (int ni = 0; ni < 4; ++ni) {
            int c = col0 + wn + ni * 16 + l15;
            float bv = bias[c];
            #pragma unroll
            for (int j = 0; j < 4; ++j) {
                float o = acc[mi][ni][j] + bv;
                if (F32OUT) ((float*)Cout)[(size_t)(rbase + j) * N + c] = o;
                else        ((u16*)Cout)[(size_t)(rbase + j) * N + c] = f2b(o);
            }
        }
    }
}

// ---------------- flash attention (QBLK=256: 8 waves, KVBLK=64) ------------
// (R14 exact: 512 thr, launch_bounds(512,4) -- no spills, 2 blocks/CU,
// kvb-seq, zero-shuffle PV via b2<->b3 V columns, lane-local VALU-L,
// builtin exp2/rcp.)
__global__ __launch_bounds__(512, 4) void attn_kernel(
    const u16* __restrict__ QKV, u16* __restrict__ ctx) {
    __shared__ u16 lK[2][64 * 64];    // K-tile [kv][d], XOR-swizzled 16B chunks
    __shared__ u16 lV[2][64 * 68];    // V^T tile [d][kv'], kv' = b2<->b3 swap, +4 pad

    int bid = blockIdx.x;
    int wg = (bid & 7) * 96 + (bid >> 3);   // XCD swizzle, nwg=768
    int bh = wg >> 2, qt = wg & 3;
    int b = bh / 12, h = bh % 12;
    int tid = threadIdx.x;
    int lane = tid & 63, wv = tid >> 6;     // wv 0..7
    int l31 = lane & 31;
    int hb = lane >> 5;

    const u16* Qb = QKV + (size_t)b * 1024 * 2304 + h * 64;
    const u16* Kb = Qb + 768;
    const u16* Vb = Qb + 1536;

    int qrow0 = qt * 256 + wv * 32;

    bf16x8 qf[4];
    #pragma unroll
    for (int ks = 0; ks < 4; ++ks)
        qf[ks] = *(const bf16x8*)(Qb + (size_t)(qrow0 + l31) * 2304 + ks * 16 + hb * 8);

    f32x16 accO0 = {}, accO1 = {};
    float lacc = 0.f;

    int krr = tid >> 3;
    int kcc = (tid & 7) ^ (krr & 7);
    bool vstage = tid < 256;
    int jj0 = (tid & 31) * 2;
    int jjs = (jj0 & ~12) | ((jj0 & 4) << 1) | ((jj0 & 8) >> 1);  // b2<->b3 swap
    int d0v = ((tid >> 5) & 7) << 3;

    load_lds16(Kb + (size_t)krr * 2304 + kcc * 8, &lK[0][(wv << 6) << 3]);
    if (vstage) {
        bf16x8 g0 = *(const bf16x8*)(Vb + (size_t)jj0 * 2304 + d0v);
        bf16x8 g1 = *(const bf16x8*)(Vb + (size_t)(jj0 + 1) * 2304 + d0v);
        const unsigned* a0 = (const unsigned*)&g0;
        const unsigned* a1 = (const unsigned*)&g1;
        #pragma unroll
        for (int w = 0; w < 4; ++w) {
            *(unsigned*)&lV[0][(d0v + 2 * w) * 68 + jjs] =
                __builtin_amdgcn_perm(a1[w], a0[w], 0x05040100);
            *(unsigned*)&lV[0][(d0v + 2 * w + 1) * 68 + jjs] =
                __builtin_amdgcn_perm(a1[w], a0[w], 0x07060302);
        }
    }
    __syncthreads();

    int cur = 0;
    for (int t = 0; t < 16; ++t) {
        bf16x8 nv0, nv1;
        if (t < 15) {
            size_t kt1 = (size_t)(t + 1) * 64;
            load_lds16(Kb + (kt1 + krr) * 2304 + kcc * 8, &lK[cur ^ 1][(wv << 6) << 3]);
            if (vstage) {
                nv0 = *(const bf16x8*)(Vb + (kt1 + jj0) * 2304 + d0v);
                nv1 = *(const bf16x8*)(Vb + (kt1 + jj0 + 1) * 2304 + d0v);
            }
        }

        #pragma unroll
        for (int kvb = 0; kvb < 2; ++kvb) {
            f32x16 accs = {};
            __builtin_amdgcn_s_setprio(1);
            #pragma unroll
            for (int ks = 0; ks < 4; ++ks) {
                bf16x8 kf = *(const bf16x8*)&lK[cur][
                    (kvb * 32 + l31) * 64 + (((ks << 1) + hb) ^ (l31 & 7)) * 8];
                accs = __builtin_amdgcn_mfma_f32_32x32x16_bf16(kf, qf[ks], accs, 0, 0, 0);
            }
            __builtin_amdgcn_s_setprio(0);

            unsigned W[8];
            float ls = 0.f;
            #pragma unroll
            for (int w = 0; w < 8; ++w) {
                float e0 = hw_exp2(accs[2 * w]);
                float e1 = hw_exp2(accs[2 * w + 1]);
                ls += e0 + e1;
                W[w] = cvt_pk_bf16(e0, e1);
            }
            lacc += ls;

            __builtin_amdgcn_s_setprio(1);
            #pragma unroll
            for (int mm = 0; mm < 2; ++mm) {
                int m = kvb * 2 + mm;
                u32x4 pw;
                pw.x = W[4 * mm];     pw.y = W[4 * mm + 1];
                pw.z = W[4 * mm + 2]; pw.w = W[4 * mm + 3];
                bf16x8 pa = *(bf16x8*)&pw;
                bf16x8 vf0 = *(const bf16x8*)&lV[cur][l31 * 68 + m * 16 + hb * 8];
                bf16x8 vf1 = *(const bf16x8*)&lV[cur][(32 + l31) * 68 + m * 16 + hb * 8];
                accO0 = __builtin_amdgcn_mfma_f32_32x32x16_bf16(pa, vf0, accO0, 0, 0, 0);
                accO1 = __builtin_amdgcn_mfma_f32_32x32x16_bf16(pa, vf1, accO1, 0, 0, 0);
            }
            __builtin_amdgcn_s_setprio(0);
        }

        if (t < 15 && vstage) {
            const unsigned* a0 = (const unsigned*)&nv0;
            const unsigned* a1 = (const unsigned*)&nv1;
            #pragma unroll
            for (int w = 0; w < 4; ++w) {
                *(unsigned*)&lV[cur ^ 1][(d0v + 2 * w) * 68 + jjs] =
                    __builtin_amdgcn_perm(a1[w], a0[w], 0x05040100);
                *(unsigned*)&lV[cur ^ 1][(d0v + 2 * w + 1) * 68 + jjs] =
                    __builtin_amdgcn_perm(a1[w], a0[w], 0x07060302);
            }
        }

        __syncthreads();
        cur ^= 1;
    }

    float lsum = lacc + __shfl_xor(lacc, 32);
    #pragma unroll
    for (int r = 0; r < 16; ++r) {
        int q = (r & 3) + 8 * (r >> 2) + hb * 4;
        float Lr = __shfl(lsum, q);
        float inv = hw_rcp(Lr);
        size_t row = (size_t)(b * 1024 + qrow0 + q);
        ctx[row * 768 + h * 64 + l31]      = f2b(accO0[r] * inv);
        ctx[row * 768 + h * 64 + 32 + l31] = f2b(accO1[r] * inv);
    }
}

// ---------------- launcher ----------------
extern "C" void kernel_launch(void* const* d_in, const int* in_sizes, int n_in,
                              void* d_out, int out_size, void* d_ws, size_t ws_size,
                              hipStream_t stream) {
    const float* x  = (const float*)d_in[0];
    const float* ci = (const float*)d_in[1];
    const float* cc = (const float*)d_in[2];
    const float* Wq = (const float*)d_in[3];
    const float* bq = (const float*)d_in[4];
    const float* Wk = (const float*)d_in[5];
    const float* bk = (const float*)d_in[6];
    const float* Wv = (const float*)d_in[7];
    const float* bv = (const float*)d_in[8];
    const float* Wo = (const float*)d_in[9];
    const float* bo = (const float*)d_in[10];
    float* out = (float*)d_out;

    unsigned char* ws = (unsigned char*)d_ws;
    size_t off = 0;
    auto alloc = [&](size_t bytes) {
        void* p = ws + off;
        off += (bytes + 255) & ~(size_t)255;
        return p;
    };
    u16*   hbuf  = (u16*)  alloc((size_t)16384 * 768 * 2);
    u16*   wqkvt = (u16*)  alloc((size_t)2304 * 768 * 2);
    u16*   wot   = (u16*)  alloc((size_t)768 * 768 * 2);
    float* biasq = (float*)alloc(2304 * 4);
    u16*   qkv   = (u16*)  alloc((size_t)16384 * 2304 * 2);
    u16*   ctx   = (u16*)  alloc((size_t)16384 * 768 * 2);

    prep_hidden<<<12288, 256, 0, stream>>>(x, hbuf);
    transpose_w<<<dim3(24, 24, 4), 256, 0, stream>>>(Wq, Wk, Wv, Wo, ci, cc, wqkvt, wot);
    bias_cat<<<9, 256, 0, stream>>>(bq, bk, bv, biasq);
    gemm_bt<0><<<2304, 256, 0, stream>>>(hbuf, wqkvt, biasq, qkv, 16384, 2304, 768, 18);
    attn_kernel<<<768, 512, 0, stream>>>(qkv, ctx);
    gemm_bt<1><<<768, 256, 0, stream>>>(ctx, wot, bo, out, 16384, 768, 768, 6);
}

// Round 20
// 180.731 us; speedup vs baseline: 1.1533x; 1.0077x over previous
//
#include <hip/hip_runtime.h>
#include <hip/hip_bf16.h>

typedef unsigned short u16;
typedef short bf16x8 __attribute__((ext_vector_type(8)));
typedef float f32x4 __attribute__((ext_vector_type(4)));
typedef float f32x16 __attribute__((ext_vector_type(16)));
typedef unsigned short u16x4 __attribute__((ext_vector_type(4)));
typedef unsigned u32x4 __attribute__((ext_vector_type(4)));

// scores pre-scaled by log2(e)/8 (folded into Wq, bq) so softmax is pure exp2
#define SCALE_Q 0.18033688011112042f

__device__ __forceinline__ u16 f2b(float f) {
    __hip_bfloat16 h = __float2bfloat16(f);   // hw v_cvt (RNE) on gfx950
    return *reinterpret_cast<u16*>(&h);
}

__device__ __forceinline__ unsigned cvt_pk_bf16(float lo, float hi) {
    unsigned r;
    asm("v_cvt_pk_bf16_f32 %0, %1, %2" : "=v"(r) : "v"(lo), "v"(hi));
    return r;
}

// single-instruction exp2/rcp via BUILTINS (hazard-safe; R10's inline-asm
// version defeated TRANS wait-state insertion -> wrong values)
#define hw_exp2 __builtin_amdgcn_exp2f
#define hw_rcp  __builtin_amdgcn_rcpf

__device__ __forceinline__ void load_lds16(const void* g, void* l) {
    __builtin_amdgcn_global_load_lds(
        (const __attribute__((address_space(1))) void*)g,
        (__attribute__((address_space(3))) void*)l, 16, 0, 0);
}

// ---------------- prep: hidden -> bf16 (ci folded into W rows) -------------
__global__ __launch_bounds__(256) void prep_hidden(
    const float* __restrict__ x, u16* __restrict__ hbuf) {
    size_t i = ((size_t)blockIdx.x * 256 + threadIdx.x) * 4;
    float4 v = *(const float4*)(x + i);
    u16x4 o;
    o.x = f2b(v.x); o.y = f2b(v.y); o.z = f2b(v.z); o.w = f2b(v.w);
    *(u16x4*)(hbuf + i) = o;
}

// ---------------- prep: transpose weights to [N][K] bf16 ----------------
// z=0..2: Wq/Wk/Wv rows scaled by channel_importance (exact: (x*ci)@W =
// x@(diag(ci)W)); z=0 also by SCALE_Q; z=3: Wo rows scaled by context_importance.
__global__ __launch_bounds__(256) void transpose_w(
    const float* __restrict__ Wq, const float* __restrict__ Wk,
    const float* __restrict__ Wv, const float* __restrict__ Wo,
    const float* __restrict__ ci, const float* __restrict__ cc,
    u16* __restrict__ wqkvt, u16* __restrict__ wot) {
    __shared__ float tile[32][33];
    int z = blockIdx.z;
    const float* src = (z == 0) ? Wq : (z == 1) ? Wk : (z == 2) ? Wv : Wo;
    u16* dst = (z < 3) ? (wqkvt + (size_t)z * 768 * 768) : wot;
    int tx = threadIdx.x & 31, ty = threadIdx.x >> 5;
    int k0 = blockIdx.x * 32, n0 = blockIdx.y * 32;
    #pragma unroll
    for (int i = ty; i < 32; i += 8) {
        float v = src[(size_t)(k0 + i) * 768 + n0 + tx];
        if (z < 3)  v *= ci[k0 + i];
        else        v *= cc[k0 + i];
        if (z == 0) v *= SCALE_Q;
        tile[i][tx] = v;
    }
    __syncthreads();
    #pragma unroll
    for (int i = ty; i < 32; i += 8)
        dst[(size_t)(n0 + i) * 768 + k0 + tx] = f2b(tile[tx][i]);
}

__global__ __launch_bounds__(256) void bias_cat(
    const float* __restrict__ bq, const float* __restrict__ bk,
    const float* __restrict__ bv, float* __restrict__ biasq) {
    int i = blockIdx.x * 256 + threadIdx.x;
    biasq[i] = (i < 768) ? bq[i] * SCALE_Q : (i < 1536) ? bk[i - 768] : bv[i - 1536];
}

// ---------------- GEMM: C[M][N] = A[M][K] @ Bt[N][K]^T + bias ----------------
// R14's proven structure exactly: 128x128 tile, BK=64, 4 waves (2x2),
// 16x16x32 MFMA (zero bank conflicts), 2 blocks/CU implicit wave overlap.
// Measured plateau: R15 ring -20%, R16 fine 2-phase -22%, R17 32x32 -7%.
template <int F32OUT>
__global__ __launch_bounds__(256) void gemm_bt(
    const u16* __restrict__ A, const u16* __restrict__ Bt,
    const float* __restrict__ bias, void* __restrict__ Cout,
    int M, int N, int K, int NTN) {
    __shared__ u16 lA[128 * 64];
    __shared__ u16 lB[128 * 64];
    int nwg = gridDim.x;
    int bid = blockIdx.x;
    int wg = ((nwg & 7) == 0) ? ((bid & 7) * (nwg >> 3) + (bid >> 3)) : bid;
    int mt = wg / NTN, nt = wg % NTN;
    int row0 = mt << 7, col0 = nt << 7;
    int tid = threadIdx.x;
    int lane = tid & 63, wv = tid >> 6;
    int wm = (wv >> 1) * 64, wn = (wv & 1) * 64;
    int l15 = lane & 15, hi = lane >> 4;

    f32x4 acc[4][4] = {};

    for (int kt = 0; kt < K; kt += 64) {
        __syncthreads();
        #pragma unroll
        for (int p = 0; p < 4; ++p) {
            int cl = p * 256 + tid;
            int rr = cl >> 3;
            int cc = (cl & 7) ^ (rr & 7);
            int lo = (p * 256 + (wv << 6)) << 3;
            load_lds16(A + (size_t)(row0 + rr) * K + kt + cc * 8, &lA[lo]);
            load_lds16(Bt + (size_t)(col0 + rr) * K + kt + cc * 8, &lB[lo]);
        }
        __syncthreads();
        __builtin_amdgcn_s_setprio(1);
        #pragma unroll
        for (int ks = 0; ks < 2; ++ks) {
            bf16x8 af[4], bf[4];
            #pragma unroll
            for (int i = 0; i < 4; ++i) {
                int ra = wm + i * 16 + l15;
                af[i] = *(const bf16x8*)&lA[ra * 64 + (((ks << 2) + hi) ^ (ra & 7)) * 8];
                int rb = wn + i * 16 + l15;
                bf[i] = *(const bf16x8*)&lB[rb * 64 + (((ks << 2) + hi) ^ (rb & 7)) * 8];
            }
            #pragma unroll
            for (int mi = 0; mi < 4; ++mi)
                #pragma unroll
                for (int ni = 0; ni < 4; ++ni)
                    acc[mi][ni] = __builtin_amdgcn_mfma_f32_16x16x32_bf16(
                        af[mi], bf[ni], acc[mi][ni], 0, 0, 0);
        }
        __builtin_amdgcn_s_setprio(0);
    }

    #pragma unroll
    for (int mi = 0; mi < 4; ++mi) {
        int rbase = row0 + wm + mi * 16 + hi * 4;
        #pragma unroll
        for (int ni = 0; ni < 4; ++ni) {
            int c = col0 + wn + ni * 16 + l15;
            float bv = bias[c];
            #pragma unroll
            for (int j = 0; j < 4; ++j) {
                float o = acc[mi][ni][j] + bv;
                if (F32OUT) ((float*)Cout)[(size_t)(rbase + j) * N + c] = o;
                else        ((u16*)Cout)[(size_t)(rbase + j) * N + c] = f2b(o);
            }
        }
    }
}

// ---------------- flash attention (QBLK=256: 8 waves, KVBLK=64) ------------
// R14/R18 exact (last-known-good; R19's KVBLK=128 port failed validation):
// 512 thr, launch_bounds(512,4) -- no spills, 2 blocks/CU, kvb-seq,
// zero-shuffle PV via b2<->b3 V columns, lane-local VALU-L, builtin exp2/rcp.
__global__ __launch_bounds__(512, 4) void attn_kernel(
    const u16* __restrict__ QKV, u16* __restrict__ ctx) {
    __shared__ u16 lK[2][64 * 64];    // K-tile [kv][d], XOR-swizzled 16B chunks
    __shared__ u16 lV[2][64 * 68];    // V^T tile [d][kv'], kv' = b2<->b3 swap, +4 pad

    int bid = blockIdx.x;
    int wg = (bid & 7) * 96 + (bid >> 3);   // XCD swizzle, nwg=768
    int bh = wg >> 2, qt = wg & 3;
    int b = bh / 12, h = bh % 12;
    int tid = threadIdx.x;
    int lane = tid & 63, wv = tid >> 6;     // wv 0..7
    int l31 = lane & 31;
    int hb = lane >> 5;

    const u16* Qb = QKV + (size_t)b * 1024 * 2304 + h * 64;
    const u16* Kb = Qb + 768;
    const u16* Vb = Qb + 1536;

    int qrow0 = qt * 256 + wv * 32;

    bf16x8 qf[4];
    #pragma unroll
    for (int ks = 0; ks < 4; ++ks)
        qf[ks] = *(const bf16x8*)(Qb + (size_t)(qrow0 + l31) * 2304 + ks * 16 + hb * 8);

    f32x16 accO0 = {}, accO1 = {};
    float lacc = 0.f;

    int krr = tid >> 3;
    int kcc = (tid & 7) ^ (krr & 7);
    bool vstage = tid < 256;
    int jj0 = (tid & 31) * 2;
    int jjs = (jj0 & ~12) | ((jj0 & 4) << 1) | ((jj0 & 8) >> 1);  // b2<->b3 swap
    int d0v = ((tid >> 5) & 7) << 3;

    load_lds16(Kb + (size_t)krr * 2304 + kcc * 8, &lK[0][(wv << 6) << 3]);
    if (vstage) {
        bf16x8 g0 = *(const bf16x8*)(Vb + (size_t)jj0 * 2304 + d0v);
        bf16x8 g1 = *(const bf16x8*)(Vb + (size_t)(jj0 + 1) * 2304 + d0v);
        const unsigned* a0 = (const unsigned*)&g0;
        const unsigned* a1 = (const unsigned*)&g1;
        #pragma unroll
        for (int w = 0; w < 4; ++w) {
            *(unsigned*)&lV[0][(d0v + 2 * w) * 68 + jjs] =
                __builtin_amdgcn_perm(a1[w], a0[w], 0x05040100);
            *(unsigned*)&lV[0][(d0v + 2 * w + 1) * 68 + jjs] =
                __builtin_amdgcn_perm(a1[w], a0[w], 0x07060302);
        }
    }
    __syncthreads();

    int cur = 0;
    for (int t = 0; t < 16; ++t) {
        bf16x8 nv0, nv1;
        if (t < 15) {
            size_t kt1 = (size_t)(t + 1) * 64;
            load_lds16(Kb + (kt1 + krr) * 2304 + kcc * 8, &lK[cur ^ 1][(wv << 6) << 3]);
            if (vstage) {
                nv0 = *(const bf16x8*)(Vb + (kt1 + jj0) * 2304 + d0v);
                nv1 = *(const bf16x8*)(Vb + (kt1 + jj0 + 1) * 2304 + d0v);
            }
        }

        #pragma unroll
        for (int kvb = 0; kvb < 2; ++kvb) {
            f32x16 accs = {};
            __builtin_amdgcn_s_setprio(1);
            #pragma unroll
            for (int ks = 0; ks < 4; ++ks) {
                bf16x8 kf = *(const bf16x8*)&lK[cur][
                    (kvb * 32 + l31) * 64 + (((ks << 1) + hb) ^ (l31 & 7)) * 8];
                accs = __builtin_amdgcn_mfma_f32_32x32x16_bf16(kf, qf[ks], accs, 0, 0, 0);
            }
            __builtin_amdgcn_s_setprio(0);

            unsigned W[8];
            float ls = 0.f;
            #pragma unroll
            for (int w = 0; w < 8; ++w) {
                float e0 = hw_exp2(accs[2 * w]);
                float e1 = hw_exp2(accs[2 * w + 1]);
                ls += e0 + e1;
                W[w] = cvt_pk_bf16(e0, e1);
            }
            lacc += ls;

            __builtin_amdgcn_s_setprio(1);
            #pragma unroll
            for (int mm = 0; mm < 2; ++mm) {
                int m = kvb * 2 + mm;
                u32x4 pw;
                pw.x = W[4 * mm];     pw.y = W[4 * mm + 1];
                pw.z = W[4 * mm + 2]; pw.w = W[4 * mm + 3];
                bf16x8 pa = *(bf16x8*)&pw;
                bf16x8 vf0 = *(const bf16x8*)&lV[cur][l31 * 68 + m * 16 + hb * 8];
                bf16x8 vf1 = *(const bf16x8*)&lV[cur][(32 + l31) * 68 + m * 16 + hb * 8];
                accO0 = __builtin_amdgcn_mfma_f32_32x32x16_bf16(pa, vf0, accO0, 0, 0, 0);
                accO1 = __builtin_amdgcn_mfma_f32_32x32x16_bf16(pa, vf1, accO1, 0, 0, 0);
            }
            __builtin_amdgcn_s_setprio(0);
        }

        if (t < 15 && vstage) {
            const unsigned* a0 = (const unsigned*)&nv0;
            const unsigned* a1 = (const unsigned*)&nv1;
            #pragma unroll
            for (int w = 0; w < 4; ++w) {
                *(unsigned*)&lV[cur ^ 1][(d0v + 2 * w) * 68 + jjs] =
                    __builtin_amdgcn_perm(a1[w], a0[w], 0x05040100);
                *(unsigned*)&lV[cur ^ 1][(d0v + 2 * w + 1) * 68 + jjs] =
                    __builtin_amdgcn_perm(a1[w], a0[w], 0x07060302);
            }
        }

        __syncthreads();
        cur ^= 1;
    }

    float lsum = lacc + __shfl_xor(lacc, 32);
    #pragma unroll
    for (int r = 0; r < 16; ++r) {
        int q = (r & 3) + 8 * (r >> 2) + hb * 4;
        float Lr = __shfl(lsum, q);
        float inv = hw_rcp(Lr);
        size_t row = (size_t)(b * 1024 + qrow0 + q);
        ctx[row * 768 + h * 64 + l31]      = f2b(accO0[r] * inv);
        ctx[row * 768 + h * 64 + 32 + l31] = f2b(accO1[r] * inv);
    }
}

// ---------------- launcher ----------------
extern "C" void kernel_launch(void* const* d_in, const int* in_sizes, int n_in,
                              void* d_out, int out_size, void* d_ws, size_t ws_size,
                              hipStream_t stream) {
    const float* x  = (const float*)d_in[0];
    const float* ci = (const float*)d_in[1];
    const float* cc = (const float*)d_in[2];
    const float* Wq = (const float*)d_in[3];
    const float* bq = (const float*)d_in[4];
    const float* Wk = (const float*)d_in[5];
    const float* bk = (const float*)d_in[6];
    const float* Wv = (const float*)d_in[7];
    const float* bv = (const float*)d_in[8];
    const float* Wo = (const float*)d_in[9];
    const float* bo = (const float*)d_in[10];
    float* out = (float*)d_out;

    unsigned char* ws = (unsigned char*)d_ws;
    size_t off = 0;
    auto alloc = [&](size_t bytes) {
        void* p = ws + off;
        off += (bytes + 255) & ~(size_t)255;
        return p;
    };
    u16*   hbuf  = (u16*)  alloc((size_t)16384 * 768 * 2);
    u16*   wqkvt = (u16*)  alloc((size_t)2304 * 768 * 2);
    u16*   wot   = (u16*)  alloc((size_t)768 * 768 * 2);
    float* biasq = (float*)alloc(2304 * 4);
    u16*   qkv   = (u16*)  alloc((size_t)16384 * 2304 * 2);
    u16*   ctx   = (u16*)  alloc((size_t)16384 * 768 * 2);

    prep_hidden<<<12288, 256, 0, stream>>>(x, hbuf);
    transpose_w<<<dim3(24, 24, 4), 256, 0, stream>>>(Wq, Wk, Wv, Wo, ci, cc, wqkvt, wot);
    bias_cat<<<9, 256, 0, stream>>>(bq, bk, bv, biasq);
    gemm_bt<0><<<2304, 256, 0, stream>>>(hbuf, wqkvt, biasq, qkv, 16384, 2304, 768, 18);
    attn_kernel<<<768, 512, 0, stream>>>(qkv, ctx);
    gemm_bt<1><<<768, 256, 0, stream>>>(ctx, wot, bo, out, 16384, 768, 768, 6);
}